// Round 5
// baseline (169.774 us; speedup 1.0000x reference)
//
#include <hip/hip_runtime.h>
#include <math.h>

#define BB 128
#define OUTROW 1259   // 2+1+256+1000

typedef float vf4 __attribute__((ext_vector_type(4)));

// A(t) = sin(H*pi*r)*cos(pi*r)/(H*sin(pi*r)),  B(t) = sin(H*pi*r)/H,  r = t - round(t)
__device__ __forceinline__ void dirichlet_ab(float t, float& A, float& Bv) {
    float r = t - rintf(t);
    float s256 = sinpif(256.0f * r);
    Bv = s256 * (1.0f / 256.0f);
    if (fabsf(r) < 1e-6f) {
        A = 1.0f;
    } else {
        float sp = sinpif(r), cp = cospif(r);
        A = Bv * cp / sp;
    }
}

// One block per (b, c). 256 threads = 4 waves; wave w owns iy = {2w, 2w+1}.
// Image loads are NON-TEMPORAL: 96MB stream must not evict MLP weights from L2.
__global__ __launch_bounds__(256) void interp_kernel(
    const float* __restrict__ image, const float* __restrict__ loc,
    const float* __restrict__ scl, float* __restrict__ pix)
{
    __shared__ float U[256 * 16];   // [p][w*4 + {A0,A1,B0,B1}]
    __shared__ float V[16 * 260];   // [ix][q] A ; [8+ix][q] B
    __shared__ float T[16 * 260];   // [iy][q] Tc ; [8+iy][q] Ts

    int bid = blockIdx.x;
    int b = bid / 3, c = bid % 3;
    int tid = threadIdx.x;
    float l0 = loc[2 * b], l1 = loc[2 * b + 1], sc = scl[b];

    {
        int p = tid;
        float tp = (float)p * (1.0f / 256.0f);
        #pragma unroll
        for (int iy = 0; iy < 8; ++iy) {
            float A, Bv;
            float y = ((float)iy * 0.125f - l0) * sc;
            dirichlet_ab(y - tp, A, Bv);
            int w = iy >> 1, o = iy & 1;
            U[p * 16 + w * 4 + o] = A;
            U[p * 16 + w * 4 + 2 + o] = Bv;
            float x = ((float)iy * 0.125f - l1) * sc;   // iy reused as ix
            dirichlet_ab(x - tp, A, Bv);
            V[iy * 260 + p] = A;
            V[(8 + iy) * 260 + p] = Bv;
        }
    }
    __syncthreads();

    int wave = tid >> 6, lane = tid & 63;
    const float* img = image + (size_t)(b * 3 + c) * 65536 + lane * 4;

    float aA0[4] = {0, 0, 0, 0}, aA1[4] = {0, 0, 0, 0};
    float aB0[4] = {0, 0, 0, 0}, aB1[4] = {0, 0, 0, 0};
    #pragma unroll 4
    for (int p = 0; p < 256; ++p) {
        vf4 v = __builtin_nontemporal_load((const vf4*)(img + p * 256));
        const float4 u = *(const float4*)(&U[p * 16 + wave * 4]);
        aA0[0] += u.x * v[0]; aA0[1] += u.x * v[1]; aA0[2] += u.x * v[2]; aA0[3] += u.x * v[3];
        aA1[0] += u.y * v[0]; aA1[1] += u.y * v[1]; aA1[2] += u.y * v[2]; aA1[3] += u.y * v[3];
        aB0[0] += u.z * v[0]; aB0[1] += u.z * v[1]; aB0[2] += u.z * v[2]; aB0[3] += u.z * v[3];
        aB1[0] += u.w * v[0]; aB1[1] += u.w * v[1]; aB1[2] += u.w * v[2]; aB1[3] += u.w * v[3];
    }
    int iy0 = wave * 2;
    int q0 = lane * 4;
    #pragma unroll
    for (int j = 0; j < 4; ++j) {
        T[iy0 * 260 + q0 + j]       = aA0[j];
        T[(iy0 + 1) * 260 + q0 + j] = aA1[j];
        T[(8 + iy0) * 260 + q0 + j]     = aB0[j];
        T[(8 + iy0 + 1) * 260 + q0 + j] = aB1[j];
    }
    __syncthreads();

    int n = tid >> 2, sub = tid & 3;
    int iy = n >> 3, ix = n & 7;
    float s = 0.f;
    #pragma unroll 8
    for (int i = 0; i < 64; ++i) {
        int q = sub + 4 * i;
        s += T[iy * 260 + q] * V[ix * 260 + q] - T[(8 + iy) * 260 + q] * V[(8 + ix) * 260 + q];
    }
    s += __shfl_xor(s, 1);
    s += __shfl_xor(s, 2);
    if (sub == 0) pix[(b * 64 + n) * 3 + c] = s;
}

// One block (1024 threads) per batch row. 16-way k-split, float4 loads,
// EXPLICIT register double-buffer prefetch: next layer's weights are issued
// while the current layer computes (weights are static -> no dependence).
__global__ __launch_bounds__(1024, 1) void mlp_kernel(
    const float* __restrict__ loc, const float* __restrict__ scl,
    const float* __restrict__ hidden, const float* __restrict__ pix,
    const float* __restrict__ w0, const float* __restrict__ b0,
    const float* __restrict__ rw, const float* __restrict__ rb,
    const float* __restrict__ wf, const float* __restrict__ bf,
    const float* __restrict__ cw0, const float* __restrict__ cb0,
    const float* __restrict__ crw, const float* __restrict__ crb,
    const float* __restrict__ cw1, const float* __restrict__ cb1,
    float* __restrict__ out)
{
    __shared__ float s_in[452];
    __shared__ float s_h[256];
    __shared__ float s_o[260];
    __shared__ float s_part[8192];
    __shared__ float s_red[32];

    int b = blockIdx.x, tid = threadIdx.x;
    int jg = tid & 63, sub = tid >> 6;   // 16-way k-split
    int j4 = jg * 4;
    float* orow = out + (size_t)b * OUTROW;

    // ---- issue w0 chunk A immediately (latency overlaps input staging) ----
    float4 wA[14];
    #pragma unroll
    for (int t = 0; t < 14; ++t)
        wA[t] = *(const float4*)(w0 + (size_t)(sub + 16 * t) * 256 + j4);

    if (tid < 2) s_in[tid] = loc[2 * b + tid];
    if (tid == 2) s_in[2] = scl[b];
    if (tid >= 256 && tid < 448) s_in[3 + (tid - 256)] = pix[b * 192 + (tid - 256)];
    if (tid >= 512 && tid < 768) s_in[195 + (tid - 512)] = hidden[b * 256 + (tid - 512)];
    __syncthreads();

    // ---- h0 = inp @ w0 + b0 (no activation) ----
    float4 acc = {0.f, 0.f, 0.f, 0.f};
    #pragma unroll
    for (int t = 0; t < 14; ++t) {
        float hv = s_in[sub + 16 * t];
        acc.x += hv * wA[t].x; acc.y += hv * wA[t].y; acc.z += hv * wA[t].z; acc.w += hv * wA[t].w;
    }
    #pragma unroll
    for (int t = 0; t < 14; ++t)
        wA[t] = *(const float4*)(w0 + (size_t)(sub + 16 * (t + 14)) * 256 + j4);
    float4 wt = {0.f, 0.f, 0.f, 0.f};
    if (sub < 3) wt = *(const float4*)(w0 + (size_t)(448 + sub) * 256 + j4);
    #pragma unroll
    for (int t = 0; t < 14; ++t) {
        float hv = s_in[sub + 16 * (t + 14)];
        acc.x += hv * wA[t].x; acc.y += hv * wA[t].y; acc.z += hv * wA[t].z; acc.w += hv * wA[t].w;
    }
    if (sub < 3) {
        float hv = s_in[448 + sub];
        acc.x += hv * wt.x; acc.y += hv * wt.y; acc.z += hv * wt.z; acc.w += hv * wt.w;
    }
    *(float4*)(&s_part[sub * 256 + j4]) = acc;

    // prefetch rw0 while the w0 reduction happens
    float4 P[8], Q[8];
    #pragma unroll
    for (int t = 0; t < 8; ++t)
        P[t] = *(const float4*)(rw + (size_t)(sub + 16 * t) * 256 + j4);
    #pragma unroll
    for (int t = 0; t < 8; ++t)
        Q[t] = *(const float4*)(rw + (size_t)(sub + 16 * (t + 8)) * 256 + j4);

    __syncthreads();
    if (tid < 256) {
        float a = b0[tid];
        #pragma unroll
        for (int s = 0; s < 16; ++s) a += s_part[s * 256 + tid];
        s_h[tid] = a;
    }
    __syncthreads();

    // ---- unified 256x256 layers 0..3 (residual relu); prefetch next ----
    const float* Wnext[4] = { rw + 65536, rw + 131072, rw + 196608, cw0 };
    #pragma unroll
    for (int L = 0; L < 4; ++L) {
        float4 a = {0.f, 0.f, 0.f, 0.f};
        #pragma unroll
        for (int t = 0; t < 8; ++t) {
            float hv = s_h[sub + 16 * t];
            a.x += hv * P[t].x; a.y += hv * P[t].y; a.z += hv * P[t].z; a.w += hv * P[t].w;
        }
        #pragma unroll
        for (int t = 0; t < 8; ++t)
            P[t] = *(const float4*)(Wnext[L] + (size_t)(sub + 16 * t) * 256 + j4);
        #pragma unroll
        for (int t = 0; t < 8; ++t) {
            float hv = s_h[sub + 16 * (t + 8)];
            a.x += hv * Q[t].x; a.y += hv * Q[t].y; a.z += hv * Q[t].z; a.w += hv * Q[t].w;
        }
        #pragma unroll
        for (int t = 0; t < 8; ++t)
            Q[t] = *(const float4*)(Wnext[L] + (size_t)(sub + 16 * (t + 8)) * 256 + j4);
        *(float4*)(&s_part[sub * 256 + j4]) = a;
        __syncthreads();
        if (tid < 256) {
            float v = rb[L * 256 + tid] + s_h[tid];
            #pragma unroll
            for (int s = 0; s < 16; ++s) v += s_part[s * 256 + tid];
            s_h[tid] = fmaxf(v, 0.f);
        }
        __syncthreads();
    }

    // ---- o = tanh(h @ wf + bf)  (256 x 259; P/Q hold cw0, keep unroll low) ----
    {
        float a0 = 0.f, a1 = 0.f, a2 = 0.f, a3 = 0.f, e = 0.f;
        #pragma unroll 4
        for (int t = 0; t < 16; ++t) {
            int k = sub + 16 * t;
            float hv = s_h[k];
            const float* w = wf + (size_t)k * 259 + j4;
            a0 += hv * w[0]; a1 += hv * w[1]; a2 += hv * w[2]; a3 += hv * w[3];
            if (jg < 3) e += hv * wf[(size_t)k * 259 + 256 + jg];
        }
        s_part[sub * 260 + j4 + 0] = a0;
        s_part[sub * 260 + j4 + 1] = a1;
        s_part[sub * 260 + j4 + 2] = a2;
        s_part[sub * 260 + j4 + 3] = a3;
        if (jg < 3) s_part[sub * 260 + 256 + jg] = e;
    }
    __syncthreads();
    if (tid < 259) {
        float a = bf[tid];
        #pragma unroll
        for (int s = 0; s < 16; ++s) a += s_part[s * 260 + tid];
        s_o[tid] = tanhf(a);
    }
    __syncthreads();

    // ---- residual state update + direct outputs ----
    if (tid < 256) {
        float nh = hidden[b * 256 + tid] + s_o[3 + tid];
        orow[3 + tid] = nh;
        s_h[tid] = nh;
    }
    if (tid == 256) orow[0] = loc[2 * b] + s_o[0];
    if (tid == 257) orow[1] = loc[2 * b + 1] + s_o[1];
    if (tid == 258) orow[2] = scl[b] + s_o[2];
    __syncthreads();

    // ---- c0 = relu(nh @ cw0 + cb0); prefetch crw ----
    {
        float4 a = {0.f, 0.f, 0.f, 0.f};
        #pragma unroll
        for (int t = 0; t < 8; ++t) {
            float hv = s_h[sub + 16 * t];
            a.x += hv * P[t].x; a.y += hv * P[t].y; a.z += hv * P[t].z; a.w += hv * P[t].w;
        }
        #pragma unroll
        for (int t = 0; t < 8; ++t)
            P[t] = *(const float4*)(crw + (size_t)(sub + 16 * t) * 256 + j4);
        #pragma unroll
        for (int t = 0; t < 8; ++t) {
            float hv = s_h[sub + 16 * (t + 8)];
            a.x += hv * Q[t].x; a.y += hv * Q[t].y; a.z += hv * Q[t].z; a.w += hv * Q[t].w;
        }
        #pragma unroll
        for (int t = 0; t < 8; ++t)
            Q[t] = *(const float4*)(crw + (size_t)(sub + 16 * (t + 8)) * 256 + j4);
        *(float4*)(&s_part[sub * 256 + j4]) = a;
        __syncthreads();
        if (tid < 256) {
            float v = cb0[tid];
            #pragma unroll
            for (int s = 0; s < 16; ++s) v += s_part[s * 256 + tid];
            s_h[tid] = fmaxf(v, 0.f);
        }
        __syncthreads();
    }

    // ---- c1 = relu(c0 @ crw + crb + c0); prefetch cw1 chunks 0,1 ----
    int sub8 = tid >> 7, jg8 = tid & 127;
    int c4 = jg8 * 4;
    {
        float4 a = {0.f, 0.f, 0.f, 0.f};
        #pragma unroll
        for (int t = 0; t < 8; ++t) {
            float hv = s_h[sub + 16 * t];
            a.x += hv * P[t].x; a.y += hv * P[t].y; a.z += hv * P[t].z; a.w += hv * P[t].w;
        }
        #pragma unroll
        for (int t = 0; t < 8; ++t) {
            float hv = s_h[sub + 16 * (t + 8)];
            a.x += hv * Q[t].x; a.y += hv * Q[t].y; a.z += hv * Q[t].z; a.w += hv * Q[t].w;
        }
        // issue cw1 chunks 0,1 (8 float4 each) into P,Q
        #pragma unroll
        for (int u = 0; u < 4; ++u) {
            int k = sub8 + 8 * u;
            const float* w = cw1 + (size_t)k * 1000;
            P[2 * u] = *(const float4*)(w + c4);
            if (jg8 < 122) P[2 * u + 1] = *(const float4*)(w + c4 + 512);
        }
        #pragma unroll
        for (int u = 0; u < 4; ++u) {
            int k = sub8 + 8 * (4 + u);
            const float* w = cw1 + (size_t)k * 1000;
            Q[2 * u] = *(const float4*)(w + c4);
            if (jg8 < 122) Q[2 * u + 1] = *(const float4*)(w + c4 + 512);
        }
        *(float4*)(&s_part[sub * 256 + j4]) = a;
        __syncthreads();
        if (tid < 256) {
            float v = crb[tid] + s_h[tid];
            #pragma unroll
            for (int s = 0; s < 16; ++s) v += s_part[s * 256 + tid];
            s_h[tid] = fmaxf(v, 0.f);
        }
        __syncthreads();
    }

    // ---- logits = c1 @ cw1 + cb1 (256x1000), ring-2 pipelined chunks ----
    {
        float4 A0 = {0.f, 0.f, 0.f, 0.f};
        float4 A1 = {0.f, 0.f, 0.f, 0.f};
        #pragma unroll
        for (int c = 0; c < 8; ++c) {
            float4* B = (c & 1) ? Q : P;
            #pragma unroll
            for (int u = 0; u < 4; ++u) {
                int k = sub8 + 8 * (4 * c + u);
                float hv = s_h[k];
                A0.x += hv * B[2*u].x; A0.y += hv * B[2*u].y; A0.z += hv * B[2*u].z; A0.w += hv * B[2*u].w;
                A1.x += hv * B[2*u+1].x; A1.y += hv * B[2*u+1].y; A1.z += hv * B[2*u+1].z; A1.w += hv * B[2*u+1].w;
            }
            if (c + 2 < 8) {
                #pragma unroll
                for (int u = 0; u < 4; ++u) {
                    int k = sub8 + 8 * (4 * (c + 2) + u);
                    const float* w = cw1 + (size_t)k * 1000;
                    B[2 * u] = *(const float4*)(w + c4);
                    if (jg8 < 122) B[2 * u + 1] = *(const float4*)(w + c4 + 512);
                }
            }
        }
        *(float4*)(&s_part[sub8 * 1024 + c4]) = A0;
        if (jg8 < 122) *(float4*)(&s_part[sub8 * 1024 + 512 + c4]) = A1;
    }
    __syncthreads();

    float lgv = -1e30f;
    if (tid < 1000) {
        float a = cb1[tid];
        #pragma unroll
        for (int s = 0; s < 8; ++s) a += s_part[s * 1024 + tid];
        lgv = a;
    }

    // ---- softmax over 1000 across 16 waves ----
    int lane = tid & 63, wid = tid >> 6;
    float m = lgv;
    #pragma unroll
    for (int off = 1; off < 64; off <<= 1) m = fmaxf(m, __shfl_xor(m, off));
    if (lane == 0) s_red[wid] = m;
    __syncthreads();
    m = s_red[0];
    #pragma unroll
    for (int w = 1; w < 16; ++w) m = fmaxf(m, s_red[w]);

    float e = (tid < 1000) ? expf(lgv - m) : 0.f;
    float lsum = e;
    #pragma unroll
    for (int off = 1; off < 64; off <<= 1) lsum += __shfl_xor(lsum, off);
    if (lane == 0) s_red[16 + wid] = lsum;
    __syncthreads();
    float total = 0.f;
    #pragma unroll
    for (int w = 0; w < 16; ++w) total += s_red[16 + w];

    if (tid < 1000) orow[259 + tid] = e / total;
}

extern "C" void kernel_launch(void* const* d_in, const int* in_sizes, int n_in,
                              void* d_out, int out_size, void* d_ws, size_t ws_size,
                              hipStream_t stream) {
    const float* image  = (const float*)d_in[0];
    const float* loc    = (const float*)d_in[1];
    const float* scl    = (const float*)d_in[2];
    const float* hidden = (const float*)d_in[3];
    const float* w0  = (const float*)d_in[4];
    const float* b0  = (const float*)d_in[5];
    const float* rw  = (const float*)d_in[6];
    const float* rb  = (const float*)d_in[7];
    const float* wf  = (const float*)d_in[8];
    const float* bf  = (const float*)d_in[9];
    const float* cw0 = (const float*)d_in[10];
    const float* cb0 = (const float*)d_in[11];
    const float* crw = (const float*)d_in[12];
    const float* crb = (const float*)d_in[13];
    const float* cw1 = (const float*)d_in[14];
    const float* cb1 = (const float*)d_in[15];

    float* pix = (float*)d_ws;   // 128*64*3 floats

    hipLaunchKernelGGL(interp_kernel, dim3(BB * 3), dim3(256), 0, stream,
                       image, loc, scl, pix);
    hipLaunchKernelGGL(mlp_kernel, dim3(BB), dim3(1024), 0, stream,
                       loc, scl, hidden, pix,
                       w0, b0, rw, rb, wf, bf, cw0, cb0, crw, crb, cw1, cb1,
                       (float*)d_out);
}

// Round 6
// 86.976 us; speedup vs baseline: 1.9520x; 1.9520x over previous
//
#include <hip/hip_runtime.h>
#include <math.h>

#define BB 128
#define OUTROW 1259   // 2+1+256+1000

typedef float vf4 __attribute__((ext_vector_type(4)));

// A(t) = sin(H*pi*r)*cos(pi*r)/(H*sin(pi*r)),  B(t) = sin(H*pi*r)/H,  r = t - round(t)
__device__ __forceinline__ void dirichlet_ab(float t, float& A, float& Bv) {
    float r = t - rintf(t);
    float s256 = sinpif(256.0f * r);
    Bv = s256 * (1.0f / 256.0f);
    if (fabsf(r) < 1e-6f) {
        A = 1.0f;
    } else {
        float sp = sinpif(r), cp = cospif(r);
        A = Bv * cp / sp;
    }
}

// ---- L2 warm: 8 teams (bid&7 ~ XCD); each team collectively reads all weights.
__device__ __forceinline__ void warm_range(const float* __restrict__ p, int n4,
                                           int slot, int tid, float& s) {
    int per = (n4 + 255) / 256;
    int lo = slot * per;
    int hi = lo + per; if (hi > n4) hi = n4;
    for (int i = lo + tid; i < hi; i += 256) {
        const float4 v = *(const float4*)(p + 4 * (size_t)i);
        s += v.x + v.y + v.z + v.w;
    }
}

__global__ __launch_bounds__(256) void warm_kernel(
    const float* __restrict__ w0, const float* __restrict__ rw,
    const float* __restrict__ wf, const float* __restrict__ cw0,
    const float* __restrict__ crw, const float* __restrict__ cw1,
    float* __restrict__ sink)
{
    int slot = (int)(blockIdx.x >> 3);      // 0..255 within team
    int tid = threadIdx.x;
    float s = 0.f;
    warm_range(w0,  28864, slot, tid, s);   // 451*256/4
    warm_range(rw,  65536, slot, tid, s);   // 4*256*256/4
    warm_range(wf,  16576, slot, tid, s);   // 256*259/4
    warm_range(cw0, 16384, slot, tid, s);
    warm_range(crw, 16384, slot, tid, s);
    warm_range(cw1, 64000, slot, tid, s);   // 256*1000/4
    if (s == 1.0e30f) sink[0] = s;          // never in practice; keeps loads live
}

// One block per (b, c). 256 threads = 4 waves; wave w owns iy = {2w, 2w+1}.
// Image loads are NON-TEMPORAL: the 96MB stream must not evict MLP weights from L2.
__global__ __launch_bounds__(256) void interp_kernel(
    const float* __restrict__ image, const float* __restrict__ loc,
    const float* __restrict__ scl, float* __restrict__ pix)
{
    __shared__ float U[256 * 16];   // [p][w*4 + {A0,A1,B0,B1}]
    __shared__ float V[16 * 260];   // [ix][q] A ; [8+ix][q] B
    __shared__ float T[16 * 260];   // [iy][q] Tc ; [8+iy][q] Ts

    int bid = blockIdx.x;
    int b = bid / 3, c = bid % 3;
    int tid = threadIdx.x;
    float l0 = loc[2 * b], l1 = loc[2 * b + 1], sc = scl[b];

    {
        int p = tid;
        float tp = (float)p * (1.0f / 256.0f);
        #pragma unroll
        for (int iy = 0; iy < 8; ++iy) {
            float A, Bv;
            float y = ((float)iy * 0.125f - l0) * sc;
            dirichlet_ab(y - tp, A, Bv);
            int w = iy >> 1, o = iy & 1;
            U[p * 16 + w * 4 + o] = A;
            U[p * 16 + w * 4 + 2 + o] = Bv;
            float x = ((float)iy * 0.125f - l1) * sc;   // iy reused as ix
            dirichlet_ab(x - tp, A, Bv);
            V[iy * 260 + p] = A;
            V[(8 + iy) * 260 + p] = Bv;
        }
    }
    __syncthreads();

    int wave = tid >> 6, lane = tid & 63;
    const float* img = image + (size_t)(b * 3 + c) * 65536 + lane * 4;

    float aA0[4] = {0, 0, 0, 0}, aA1[4] = {0, 0, 0, 0};
    float aB0[4] = {0, 0, 0, 0}, aB1[4] = {0, 0, 0, 0};
    #pragma unroll 4
    for (int p = 0; p < 256; ++p) {
        vf4 v = __builtin_nontemporal_load((const vf4*)(img + p * 256));
        const float4 u = *(const float4*)(&U[p * 16 + wave * 4]);
        aA0[0] += u.x * v[0]; aA0[1] += u.x * v[1]; aA0[2] += u.x * v[2]; aA0[3] += u.x * v[3];
        aA1[0] += u.y * v[0]; aA1[1] += u.y * v[1]; aA1[2] += u.y * v[2]; aA1[3] += u.y * v[3];
        aB0[0] += u.z * v[0]; aB0[1] += u.z * v[1]; aB0[2] += u.z * v[2]; aB0[3] += u.z * v[3];
        aB1[0] += u.w * v[0]; aB1[1] += u.w * v[1]; aB1[2] += u.w * v[2]; aB1[3] += u.w * v[3];
    }
    int iy0 = wave * 2;
    int q0 = lane * 4;
    #pragma unroll
    for (int j = 0; j < 4; ++j) {
        T[iy0 * 260 + q0 + j]       = aA0[j];
        T[(iy0 + 1) * 260 + q0 + j] = aA1[j];
        T[(8 + iy0) * 260 + q0 + j]     = aB0[j];
        T[(8 + iy0 + 1) * 260 + q0 + j] = aB1[j];
    }
    __syncthreads();

    int n = tid >> 2, sub = tid & 3;
    int iy = n >> 3, ix = n & 7;
    float s = 0.f;
    #pragma unroll 8
    for (int i = 0; i < 64; ++i) {
        int q = sub + 4 * i;
        s += T[iy * 260 + q] * V[ix * 260 + q] - T[(8 + iy) * 260 + q] * V[(8 + ix) * 260 + q];
    }
    s += __shfl_xor(s, 1);
    s += __shfl_xor(s, 2);
    if (sub == 0) pix[(b * 64 + n) * 3 + c] = s;
}

// One block (1024 threads) per batch row. 16-way k-split, float4 loads.
// Full-unroll load loops WITHIN each layer (transient 16 float4 in flight),
// no persistent register arrays across phases (R3/R5 spill lesson).
// All biases staged to LDS up front so layers have no dependent bias misses.
__global__ __launch_bounds__(1024, 1) void mlp_kernel(
    const float* __restrict__ loc, const float* __restrict__ scl,
    const float* __restrict__ hidden, const float* __restrict__ pix,
    const float* __restrict__ w0, const float* __restrict__ b0,
    const float* __restrict__ rw, const float* __restrict__ rb,
    const float* __restrict__ wf, const float* __restrict__ bf,
    const float* __restrict__ cw0, const float* __restrict__ cb0,
    const float* __restrict__ crw, const float* __restrict__ crb,
    const float* __restrict__ cw1, const float* __restrict__ cb1,
    float* __restrict__ out)
{
    __shared__ float s_in[452];
    __shared__ float s_h[256];
    __shared__ float s_o[260];
    __shared__ float s_part[8192];
    __shared__ float s_red[32];
    __shared__ float s_b0[256], s_rb[1024], s_bf[260], s_cb0[256], s_crb[256], s_cb1[1000];

    int b = blockIdx.x, tid = threadIdx.x;
    int jg = tid & 63, sub = tid >> 6;   // 16-way k-split
    int j4 = jg * 4;
    float* orow = out + (size_t)b * OUTROW;

    // stage inputs + all biases (independent coalesced loads, overlap each other)
    if (tid < 2) s_in[tid] = loc[2 * b + tid];
    if (tid == 2) s_in[2] = scl[b];
    if (tid >= 256 && tid < 448) s_in[3 + (tid - 256)] = pix[b * 192 + (tid - 256)];
    if (tid >= 512 && tid < 768) s_in[195 + (tid - 512)] = hidden[b * 256 + (tid - 512)];
    if (tid < 256) s_b0[tid] = b0[tid];
    s_rb[tid] = rb[tid];
    if (tid < 259) s_bf[tid] = bf[tid];
    if (tid >= 256 && tid < 512) s_cb0[tid - 256] = cb0[tid - 256];
    if (tid >= 512 && tid < 768) s_crb[tid - 512] = crb[tid - 512];
    if (tid < 1000) s_cb1[tid] = cb1[tid];
    __syncthreads();

    // ---- h0 = inp @ w0 + b0   (451 x 256), two half-passes of 14 ----
    {
        float4 acc = {0.f, 0.f, 0.f, 0.f};
        #pragma unroll
        for (int t = 0; t < 14; ++t) {
            int k = sub + 16 * t;
            float hv = s_in[k];
            float4 w = *(const float4*)(w0 + (size_t)k * 256 + j4);
            acc.x += hv * w.x; acc.y += hv * w.y; acc.z += hv * w.z; acc.w += hv * w.w;
        }
        #pragma unroll
        for (int t = 14; t < 28; ++t) {
            int k = sub + 16 * t;
            float hv = s_in[k];
            float4 w = *(const float4*)(w0 + (size_t)k * 256 + j4);
            acc.x += hv * w.x; acc.y += hv * w.y; acc.z += hv * w.z; acc.w += hv * w.w;
        }
        if (sub < 3) {
            int k = 448 + sub;
            float hv = s_in[k];
            float4 w = *(const float4*)(w0 + (size_t)k * 256 + j4);
            acc.x += hv * w.x; acc.y += hv * w.y; acc.z += hv * w.z; acc.w += hv * w.w;
        }
        *(float4*)(&s_part[sub * 256 + j4]) = acc;
    }
    __syncthreads();
    if (tid < 256) {
        float a = s_b0[tid];
        #pragma unroll
        for (int s = 0; s < 16; ++s) a += s_part[s * 256 + tid];
        s_h[tid] = a;
    }
    __syncthreads();

    // ---- 4 residual layers: h = relu(h@rw + rb + h), full-unroll 16 ----
    #pragma unroll 1
    for (int L = 0; L < 4; ++L) {
        const float* W = rw + (size_t)L * 65536;
        float4 a = {0.f, 0.f, 0.f, 0.f};
        #pragma unroll
        for (int t = 0; t < 16; ++t) {
            int k = sub + 16 * t;
            float hv = s_h[k];
            float4 w = *(const float4*)(W + (size_t)k * 256 + j4);
            a.x += hv * w.x; a.y += hv * w.y; a.z += hv * w.z; a.w += hv * w.w;
        }
        *(float4*)(&s_part[sub * 256 + j4]) = a;
        __syncthreads();
        if (tid < 256) {
            float v = s_rb[L * 256 + tid] + s_h[tid];
            #pragma unroll
            for (int s = 0; s < 16; ++s) v += s_part[s * 256 + tid];
            s_h[tid] = fmaxf(v, 0.f);
        }
        __syncthreads();
    }

    // ---- o = tanh(h @ wf + bf)  (256 x 259, stride 259 -> scalar loads) ----
    {
        float a0 = 0.f, a1 = 0.f, a2 = 0.f, a3 = 0.f, e = 0.f;
        #pragma unroll 8
        for (int t = 0; t < 16; ++t) {
            int k = sub + 16 * t;
            float hv = s_h[k];
            const float* w = wf + (size_t)k * 259 + j4;
            a0 += hv * w[0]; a1 += hv * w[1]; a2 += hv * w[2]; a3 += hv * w[3];
            if (jg < 3) e += hv * wf[(size_t)k * 259 + 256 + jg];
        }
        s_part[sub * 260 + j4 + 0] = a0;
        s_part[sub * 260 + j4 + 1] = a1;
        s_part[sub * 260 + j4 + 2] = a2;
        s_part[sub * 260 + j4 + 3] = a3;
        if (jg < 3) s_part[sub * 260 + 256 + jg] = e;
    }
    __syncthreads();
    if (tid < 259) {
        float a = s_bf[tid];
        #pragma unroll
        for (int s = 0; s < 16; ++s) a += s_part[s * 260 + tid];
        s_o[tid] = tanhf(a);
    }
    __syncthreads();

    // ---- residual state update + direct outputs (inputs from LDS) ----
    if (tid < 256) {
        float nh = s_in[195 + tid] + s_o[3 + tid];
        orow[3 + tid] = nh;
        s_h[tid] = nh;
    }
    if (tid == 256) orow[0] = s_in[0] + s_o[0];
    if (tid == 257) orow[1] = s_in[1] + s_o[1];
    if (tid == 258) orow[2] = s_in[2] + s_o[2];
    __syncthreads();

    // ---- c0 = relu(nh @ cw0 + cb0), full-unroll 16 ----
    {
        float4 a = {0.f, 0.f, 0.f, 0.f};
        #pragma unroll
        for (int t = 0; t < 16; ++t) {
            int k = sub + 16 * t;
            float hv = s_h[k];
            float4 w = *(const float4*)(cw0 + (size_t)k * 256 + j4);
            a.x += hv * w.x; a.y += hv * w.y; a.z += hv * w.z; a.w += hv * w.w;
        }
        *(float4*)(&s_part[sub * 256 + j4]) = a;
    }
    __syncthreads();
    if (tid < 256) {
        float v = s_cb0[tid];
        #pragma unroll
        for (int s = 0; s < 16; ++s) v += s_part[s * 256 + tid];
        s_h[tid] = fmaxf(v, 0.f);
    }
    __syncthreads();

    // ---- c1 = relu(c0 @ crw + crb + c0), full-unroll 16 ----
    {
        float4 a = {0.f, 0.f, 0.f, 0.f};
        #pragma unroll
        for (int t = 0; t < 16; ++t) {
            int k = sub + 16 * t;
            float hv = s_h[k];
            float4 w = *(const float4*)(crw + (size_t)k * 256 + j4);
            a.x += hv * w.x; a.y += hv * w.y; a.z += hv * w.z; a.w += hv * w.w;
        }
        *(float4*)(&s_part[sub * 256 + j4]) = a;
        __syncthreads();
        if (tid < 256) {
            float v = s_crb[tid] + s_h[tid];
            #pragma unroll
            for (int s = 0; s < 16; ++s) v += s_part[s * 256 + tid];
            s_h[tid] = fmaxf(v, 0.f);
        }
        __syncthreads();
    }

    // ---- logits = c1 @ cw1 + cb1  (256 x 1000) ----
    {
        int sub8 = tid >> 7, jg8 = tid & 127;
        int c4 = jg8 * 4;
        float4 acc0 = {0.f, 0.f, 0.f, 0.f};
        float4 acc1 = {0.f, 0.f, 0.f, 0.f};
        #pragma unroll 8
        for (int t = 0; t < 32; ++t) {
            int k = sub8 + 8 * t;
            float hv = s_h[k];
            const float* w = cw1 + (size_t)k * 1000;
            float4 wa = *(const float4*)(w + c4);
            acc0.x += hv * wa.x; acc0.y += hv * wa.y; acc0.z += hv * wa.z; acc0.w += hv * wa.w;
            if (jg8 < 122) {
                float4 wb = *(const float4*)(w + c4 + 512);
                acc1.x += hv * wb.x; acc1.y += hv * wb.y; acc1.z += hv * wb.z; acc1.w += hv * wb.w;
            }
        }
        *(float4*)(&s_part[sub8 * 1024 + c4]) = acc0;
        if (jg8 < 122) *(float4*)(&s_part[sub8 * 1024 + 512 + c4]) = acc1;
    }
    __syncthreads();

    float lgv = -1e30f;
    if (tid < 1000) {
        float a = s_cb1[tid];
        #pragma unroll
        for (int s = 0; s < 8; ++s) a += s_part[s * 1024 + tid];
        lgv = a;
    }

    // ---- softmax over 1000 across 16 waves ----
    int lane = tid & 63, wid = tid >> 6;
    float m = lgv;
    #pragma unroll
    for (int off = 1; off < 64; off <<= 1) m = fmaxf(m, __shfl_xor(m, off));
    if (lane == 0) s_red[wid] = m;
    __syncthreads();
    m = s_red[0];
    #pragma unroll
    for (int w = 1; w < 16; ++w) m = fmaxf(m, s_red[w]);

    float e = (tid < 1000) ? expf(lgv - m) : 0.f;
    float lsum = e;
    #pragma unroll
    for (int off = 1; off < 64; off <<= 1) lsum += __shfl_xor(lsum, off);
    if (lane == 0) s_red[16 + wid] = lsum;
    __syncthreads();
    float total = 0.f;
    #pragma unroll
    for (int w = 0; w < 16; ++w) total += s_red[16 + w];

    if (tid < 1000) orow[259 + tid] = e / total;
}

extern "C" void kernel_launch(void* const* d_in, const int* in_sizes, int n_in,
                              void* d_out, int out_size, void* d_ws, size_t ws_size,
                              hipStream_t stream) {
    const float* image  = (const float*)d_in[0];
    const float* loc    = (const float*)d_in[1];
    const float* scl    = (const float*)d_in[2];
    const float* hidden = (const float*)d_in[3];
    const float* w0  = (const float*)d_in[4];
    const float* b0  = (const float*)d_in[5];
    const float* rw  = (const float*)d_in[6];
    const float* rb  = (const float*)d_in[7];
    const float* wf  = (const float*)d_in[8];
    const float* bf  = (const float*)d_in[9];
    const float* cw0 = (const float*)d_in[10];
    const float* cb0 = (const float*)d_in[11];
    const float* crw = (const float*)d_in[12];
    const float* crb = (const float*)d_in[13];
    const float* cw1 = (const float*)d_in[14];
    const float* cb1 = (const float*)d_in[15];

    float* pix = (float*)d_ws;   // 128*64*3 floats

    hipLaunchKernelGGL(warm_kernel, dim3(2048), dim3(256), 0, stream,
                       w0, rw, wf, cw0, crw, cw1, pix);
    hipLaunchKernelGGL(interp_kernel, dim3(BB * 3), dim3(256), 0, stream,
                       image, loc, scl, pix);
    hipLaunchKernelGGL(mlp_kernel, dim3(BB), dim3(1024), 0, stream,
                       loc, scl, hidden, pix,
                       w0, b0, rw, rb, wf, bf, cw0, cb0, crw, crb, cw1, cb1,
                       (float*)d_out);
}

// Round 7
// 85.522 us; speedup vs baseline: 1.9852x; 1.0170x over previous
//
#include <hip/hip_runtime.h>
#include <math.h>

#define BB 128
#define OUTROW 1259   // 2+1+256+1000

typedef float vf4 __attribute__((ext_vector_type(4)));

// A(t) = sin(H*pi*r)*cos(pi*r)/(H*sin(pi*r)),  B(t) = sin(H*pi*r)/H,  r = t - round(t)
__device__ __forceinline__ void dirichlet_ab(float t, float& A, float& Bv) {
    float r = t - rintf(t);
    float s256 = sinpif(256.0f * r);
    Bv = s256 * (1.0f / 256.0f);
    if (fabsf(r) < 1e-6f) {
        A = 1.0f;
    } else {
        float sp = sinpif(r), cp = cospif(r);
        A = Bv * cp / sp;
    }
}

// One block per (b, c). 256 threads = 4 waves; wave w owns iy = {2w, 2w+1}.
// Non-temporal image loads: 96MB single-use stream, keep weights in L2.
__global__ __launch_bounds__(256) void interp_kernel(
    const float* __restrict__ image, const float* __restrict__ loc,
    const float* __restrict__ scl, float* __restrict__ pix)
{
    __shared__ float U[256 * 16];
    __shared__ float V[16 * 260];
    __shared__ float T[16 * 260];

    int bid = blockIdx.x;
    int b = bid / 3, c = bid % 3;
    int tid = threadIdx.x;
    float l0 = loc[2 * b], l1 = loc[2 * b + 1], sc = scl[b];

    {
        int p = tid;
        float tp = (float)p * (1.0f / 256.0f);
        #pragma unroll
        for (int iy = 0; iy < 8; ++iy) {
            float A, Bv;
            float y = ((float)iy * 0.125f - l0) * sc;
            dirichlet_ab(y - tp, A, Bv);
            int w = iy >> 1, o = iy & 1;
            U[p * 16 + w * 4 + o] = A;
            U[p * 16 + w * 4 + 2 + o] = Bv;
            float x = ((float)iy * 0.125f - l1) * sc;
            dirichlet_ab(x - tp, A, Bv);
            V[iy * 260 + p] = A;
            V[(8 + iy) * 260 + p] = Bv;
        }
    }
    __syncthreads();

    int wave = tid >> 6, lane = tid & 63;
    const float* img = image + (size_t)(b * 3 + c) * 65536 + lane * 4;

    float aA0[4] = {0, 0, 0, 0}, aA1[4] = {0, 0, 0, 0};
    float aB0[4] = {0, 0, 0, 0}, aB1[4] = {0, 0, 0, 0};
    #pragma unroll 4
    for (int p = 0; p < 256; ++p) {
        vf4 v = __builtin_nontemporal_load((const vf4*)(img + p * 256));
        const float4 u = *(const float4*)(&U[p * 16 + wave * 4]);
        aA0[0] += u.x * v[0]; aA0[1] += u.x * v[1]; aA0[2] += u.x * v[2]; aA0[3] += u.x * v[3];
        aA1[0] += u.y * v[0]; aA1[1] += u.y * v[1]; aA1[2] += u.y * v[2]; aA1[3] += u.y * v[3];
        aB0[0] += u.z * v[0]; aB0[1] += u.z * v[1]; aB0[2] += u.z * v[2]; aB0[3] += u.z * v[3];
        aB1[0] += u.w * v[0]; aB1[1] += u.w * v[1]; aB1[2] += u.w * v[2]; aB1[3] += u.w * v[3];
    }
    int iy0 = wave * 2;
    int q0 = lane * 4;
    #pragma unroll
    for (int j = 0; j < 4; ++j) {
        T[iy0 * 260 + q0 + j]       = aA0[j];
        T[(iy0 + 1) * 260 + q0 + j] = aA1[j];
        T[(8 + iy0) * 260 + q0 + j]     = aB0[j];
        T[(8 + iy0 + 1) * 260 + q0 + j] = aB1[j];
    }
    __syncthreads();

    int n = tid >> 2, sub = tid & 3;
    int iy = n >> 3, ix = n & 7;
    float s = 0.f;
    #pragma unroll 8
    for (int i = 0; i < 64; ++i) {
        int q = sub + 4 * i;
        s += T[iy * 260 + q] * V[ix * 260 + q] - T[(8 + iy) * 260 + q] * V[(8 + ix) * 260 + q];
    }
    s += __shfl_xor(s, 1);
    s += __shfl_xor(s, 2);
    if (sub == 0) pix[(b * 64 + n) * 3 + c] = s;
}

// 256x256 GEMV piece: all 16 float4 weight loads issued first (two-loop
// pattern, statically-indexed arrays stay in registers), then LDS reads,
// then FMAs. Transient-only register use (~90 VGPR).
__device__ __forceinline__ void gemv256(const float* __restrict__ W,
                                        const float* __restrict__ s_src,
                                        float* __restrict__ s_part,
                                        int sub, int j4)
{
    float4 wv[16];
    float hv[16];
    #pragma unroll
    for (int t = 0; t < 16; ++t)
        wv[t] = *(const float4*)(W + (size_t)(sub + 16 * t) * 256 + j4);
    #pragma unroll
    for (int t = 0; t < 16; ++t)
        hv[t] = s_src[sub + 16 * t];
    float4 a = {0.f, 0.f, 0.f, 0.f};
    #pragma unroll
    for (int t = 0; t < 16; ++t) {
        a.x += hv[t] * wv[t].x; a.y += hv[t] * wv[t].y;
        a.z += hv[t] * wv[t].z; a.w += hv[t] * wv[t].w;
    }
    *(float4*)(&s_part[sub * 256 + j4]) = a;
}

// Main per-row chain: h0, 4 residual layers, wf/tanh, state update, cw0, crw.
// Writes out[0..258] and c1 -> workspace for the parallel classifier kernels.
__global__ __launch_bounds__(1024, 1) void mlp_main(
    const float* __restrict__ loc, const float* __restrict__ scl,
    const float* __restrict__ hidden, const float* __restrict__ pix,
    const float* __restrict__ w0, const float* __restrict__ b0,
    const float* __restrict__ rw, const float* __restrict__ rb,
    const float* __restrict__ wf, const float* __restrict__ bf,
    const float* __restrict__ cw0, const float* __restrict__ cb0,
    const float* __restrict__ crw, const float* __restrict__ crb,
    float* __restrict__ c1buf, float* __restrict__ out)
{
    __shared__ float s_in[452];
    __shared__ float s_h[256];
    __shared__ float s_c[256];
    __shared__ float s_o[260];
    __shared__ float s_part[16 * 260];
    __shared__ float s_b0[256], s_rb[1024], s_bf[260], s_cb0[256], s_crb[256];

    int b = blockIdx.x, tid = threadIdx.x;
    int jg = tid & 63, sub = tid >> 6;
    int j4 = jg * 4;
    float* orow = out + (size_t)b * OUTROW;

    if (tid < 2) s_in[tid] = loc[2 * b + tid];
    if (tid == 2) s_in[2] = scl[b];
    if (tid >= 256 && tid < 448) s_in[3 + (tid - 256)] = pix[b * 192 + (tid - 256)];
    if (tid >= 512 && tid < 768) s_in[195 + (tid - 512)] = hidden[b * 256 + (tid - 512)];
    if (tid < 256) s_b0[tid] = b0[tid];
    s_rb[tid] = rb[tid];
    if (tid < 259) s_bf[tid] = bf[tid];
    if (tid >= 256 && tid < 512) s_cb0[tid - 256] = cb0[tid - 256];
    if (tid >= 512 && tid < 768) s_crb[tid - 512] = crb[tid - 512];
    __syncthreads();

    // ---- h0 = inp @ w0 + b0 (451 x 256): two 14-deep passes + tail ----
    {
        float4 acc = {0.f, 0.f, 0.f, 0.f};
        {
            float4 wv[14]; float hv[14];
            #pragma unroll
            for (int t = 0; t < 14; ++t)
                wv[t] = *(const float4*)(w0 + (size_t)(sub + 16 * t) * 256 + j4);
            #pragma unroll
            for (int t = 0; t < 14; ++t) hv[t] = s_in[sub + 16 * t];
            #pragma unroll
            for (int t = 0; t < 14; ++t) {
                acc.x += hv[t] * wv[t].x; acc.y += hv[t] * wv[t].y;
                acc.z += hv[t] * wv[t].z; acc.w += hv[t] * wv[t].w;
            }
        }
        {
            float4 wv[14]; float hv[14];
            #pragma unroll
            for (int t = 0; t < 14; ++t)
                wv[t] = *(const float4*)(w0 + (size_t)(sub + 16 * (t + 14)) * 256 + j4);
            #pragma unroll
            for (int t = 0; t < 14; ++t) hv[t] = s_in[sub + 16 * (t + 14)];
            #pragma unroll
            for (int t = 0; t < 14; ++t) {
                acc.x += hv[t] * wv[t].x; acc.y += hv[t] * wv[t].y;
                acc.z += hv[t] * wv[t].z; acc.w += hv[t] * wv[t].w;
            }
        }
        if (sub < 3) {
            int k = 448 + sub;
            float hv = s_in[k];
            float4 w = *(const float4*)(w0 + (size_t)k * 256 + j4);
            acc.x += hv * w.x; acc.y += hv * w.y; acc.z += hv * w.z; acc.w += hv * w.w;
        }
        *(float4*)(&s_part[sub * 256 + j4]) = acc;
    }
    __syncthreads();
    if (tid < 256) {
        float a = s_b0[tid];
        #pragma unroll
        for (int s = 0; s < 16; ++s) a += s_part[s * 256 + tid];
        s_h[tid] = a;
    }
    __syncthreads();

    // ---- 4 residual layers ----
    #pragma unroll 1
    for (int L = 0; L < 4; ++L) {
        gemv256(rw + (size_t)L * 65536, s_h, s_part, sub, j4);
        __syncthreads();
        if (tid < 256) {
            float v = s_rb[L * 256 + tid] + s_h[tid];
            #pragma unroll
            for (int s = 0; s < 16; ++s) v += s_part[s * 256 + tid];
            s_h[tid] = fmaxf(v, 0.f);
        }
        __syncthreads();
    }

    // ---- o = tanh(h @ wf + bf) (256 x 259) ----
    {
        float a0 = 0.f, a1 = 0.f, a2 = 0.f, a3 = 0.f, e = 0.f;
        #pragma unroll 8
        for (int t = 0; t < 16; ++t) {
            int k = sub + 16 * t;
            float hv = s_h[k];
            const float* w = wf + (size_t)k * 259 + j4;
            a0 += hv * w[0]; a1 += hv * w[1]; a2 += hv * w[2]; a3 += hv * w[3];
            if (jg < 3) e += hv * wf[(size_t)k * 259 + 256 + jg];
        }
        s_part[sub * 260 + j4 + 0] = a0;
        s_part[sub * 260 + j4 + 1] = a1;
        s_part[sub * 260 + j4 + 2] = a2;
        s_part[sub * 260 + j4 + 3] = a3;
        if (jg < 3) s_part[sub * 260 + 256 + jg] = e;
    }
    __syncthreads();
    if (tid < 259) {
        float a = s_bf[tid];
        #pragma unroll
        for (int s = 0; s < 16; ++s) a += s_part[s * 260 + tid];
        s_o[tid] = tanhf(a);
    }
    __syncthreads();

    // ---- state update + direct outputs ----
    if (tid < 256) {
        float nh = s_in[195 + tid] + s_o[3 + tid];
        orow[3 + tid] = nh;
        s_h[tid] = nh;
    }
    if (tid == 256) orow[0] = s_in[0] + s_o[0];
    if (tid == 257) orow[1] = s_in[1] + s_o[1];
    if (tid == 258) orow[2] = s_in[2] + s_o[2];
    __syncthreads();

    // ---- c0 = relu(nh @ cw0 + cb0) ----
    gemv256(cw0, s_h, s_part, sub, j4);
    __syncthreads();
    if (tid < 256) {
        float v = s_cb0[tid];
        #pragma unroll
        for (int s = 0; s < 16; ++s) v += s_part[s * 256 + tid];
        s_c[tid] = fmaxf(v, 0.f);
    }
    __syncthreads();

    // ---- c1 = relu(c0 @ crw + crb + c0) -> c1buf ----
    gemv256(crw, s_c, s_part, sub, j4);
    __syncthreads();
    if (tid < 256) {
        float v = s_crb[tid] + s_c[tid];
        #pragma unroll
        for (int s = 0; s < 16; ++s) v += s_part[s * 256 + tid];
        c1buf[b * 256 + tid] = fmaxf(v, 0.f);
    }
}

// logits = c1 @ cw1 + cb1, tiled as (row b, col-slice s) over 128x8 blocks.
// 1024 threads: 32-way k-split x 32 float4 column groups (128 cols/slice).
__global__ __launch_bounds__(1024, 1) void logits_kernel(
    const float* __restrict__ c1buf, const float* __restrict__ cw1,
    const float* __restrict__ cb1, float* __restrict__ logits)
{
    __shared__ float s_c1[256];
    __shared__ float s_part[32 * 128];

    int b = blockIdx.x, s = blockIdx.y, tid = threadIdx.x;
    if (tid < 256) s_c1[tid] = c1buf[b * 256 + tid];
    __syncthreads();

    int cg = tid & 31, sub = tid >> 5;    // col group (4 cols), k-sub (32-way)
    int c4 = cg * 4;
    int col0 = s * 128 + c4;
    bool valid = (col0 + 3) < 1000;       // slice 7: cg<26 exactly covers 896..999

    float4 acc = {0.f, 0.f, 0.f, 0.f};
    if (valid) {
        float4 wv[8]; float hv[8];
        #pragma unroll
        for (int t = 0; t < 8; ++t)
            wv[t] = *(const float4*)(cw1 + (size_t)(sub + 32 * t) * 1000 + col0);
        #pragma unroll
        for (int t = 0; t < 8; ++t) hv[t] = s_c1[sub + 32 * t];
        #pragma unroll
        for (int t = 0; t < 8; ++t) {
            acc.x += hv[t] * wv[t].x; acc.y += hv[t] * wv[t].y;
            acc.z += hv[t] * wv[t].z; acc.w += hv[t] * wv[t].w;
        }
    }
    *(float4*)(&s_part[sub * 128 + c4]) = acc;
    __syncthreads();

    if (tid < 128) {
        int col = s * 128 + tid;
        if (col < 1000) {
            float a = cb1[col];
            #pragma unroll
            for (int ss = 0; ss < 32; ++ss) a += s_part[ss * 128 + tid];
            logits[(size_t)b * 1000 + col] = a;
        }
    }
}

// Per-row softmax over 1000 logits -> out[259..1258].
__global__ __launch_bounds__(1024) void softmax_kernel(
    const float* __restrict__ logits, float* __restrict__ out)
{
    __shared__ float s_red[32];
    int b = blockIdx.x, tid = threadIdx.x;
    float* orow = out + (size_t)b * OUTROW;

    float lgv = (tid < 1000) ? logits[(size_t)b * 1000 + tid] : -1e30f;

    int lane = tid & 63, wid = tid >> 6;
    float m = lgv;
    #pragma unroll
    for (int off = 1; off < 64; off <<= 1) m = fmaxf(m, __shfl_xor(m, off));
    if (lane == 0) s_red[wid] = m;
    __syncthreads();
    m = s_red[0];
    #pragma unroll
    for (int w = 1; w < 16; ++w) m = fmaxf(m, s_red[w]);

    float e = (tid < 1000) ? expf(lgv - m) : 0.f;
    float lsum = e;
    #pragma unroll
    for (int off = 1; off < 64; off <<= 1) lsum += __shfl_xor(lsum, off);
    if (lane == 0) s_red[16 + wid] = lsum;
    __syncthreads();
    float total = 0.f;
    #pragma unroll
    for (int w = 0; w < 16; ++w) total += s_red[16 + w];

    if (tid < 1000) orow[259 + tid] = e / total;
}

extern "C" void kernel_launch(void* const* d_in, const int* in_sizes, int n_in,
                              void* d_out, int out_size, void* d_ws, size_t ws_size,
                              hipStream_t stream) {
    const float* image  = (const float*)d_in[0];
    const float* loc    = (const float*)d_in[1];
    const float* scl    = (const float*)d_in[2];
    const float* hidden = (const float*)d_in[3];
    const float* w0  = (const float*)d_in[4];
    const float* b0  = (const float*)d_in[5];
    const float* rw  = (const float*)d_in[6];
    const float* rb  = (const float*)d_in[7];
    const float* wf  = (const float*)d_in[8];
    const float* bf  = (const float*)d_in[9];
    const float* cw0 = (const float*)d_in[10];
    const float* cb0 = (const float*)d_in[11];
    const float* crw = (const float*)d_in[12];
    const float* crb = (const float*)d_in[13];
    const float* cw1 = (const float*)d_in[14];
    const float* cb1 = (const float*)d_in[15];

    float* ws     = (float*)d_ws;
    float* pix    = ws;                 // 128*192 = 24576 floats
    float* c1buf  = ws + 24576;         // 128*256 = 32768 floats
    float* logits = ws + 24576 + 32768; // 128*1000 floats

    hipLaunchKernelGGL(interp_kernel, dim3(BB * 3), dim3(256), 0, stream,
                       image, loc, scl, pix);
    hipLaunchKernelGGL(mlp_main, dim3(BB), dim3(1024), 0, stream,
                       loc, scl, hidden, pix,
                       w0, b0, rw, rb, wf, bf, cw0, cb0, crw, crb,
                       c1buf, (float*)d_out);
    hipLaunchKernelGGL(logits_kernel, dim3(BB, 8), dim3(1024), 0, stream,
                       c1buf, cw1, cb1, logits);
    hipLaunchKernelGGL(softmax_kernel, dim3(BB), dim3(1024), 0, stream,
                       logits, (float*)d_out);
}